// Round 5
// baseline (217.095 us; speedup 1.0000x reference)
//
#include <hip/hip_runtime.h>
#include <math.h>

// Shapes fixed by setup_inputs(): bs=2, m=16, v=16, L=40320, P=32, beta=1
#define BS 2
#define M 16
#define V 16
#define NROWB 136           // per-batch rows: 16 target + 120 i<j pairs
#define NROWS 272           // BS * NROWB
#define PMASK 32
#define NPB 630             // l-chunks = blocks per batch (L = NPB*64)
#define NE 8704             // NROWS*PMASK output elements
#define PBSTRIDE 8704       // floats per pb step in partial (2*136*32)
#define SPLIT 30            // k3a pb-groups
#define QPB 21              // pb per group (630 = 30*21)

typedef __attribute__((ext_vector_type(8))) short bf16x8;
typedef __attribute__((ext_vector_type(4))) float f32x4;
typedef __attribute__((ext_vector_type(4))) unsigned int u32x4;

static __device__ __forceinline__ unsigned short f2bf(float x) {
    unsigned int u = __float_as_uint(x);
    unsigned int r = (u + 0x7FFFu + ((u >> 16) & 1u)) >> 16;
    return (unsigned short)r;
}

// -------- one v-slice of pair/target accumulation (same math/order) --------
template<int W>
static __device__ __forceinline__ void pairs_one(
    const float* __restrict__ xr,     // 16 raw preds values for this v
    float s,                          // scale[v]*weights[l]
    float y,                          // prescaled target (W==0 only)
    float* __restrict__ acc)
{
    const int base = (W == 0) ? 0 : 34 * W - 16;  // first pair idx
    const int npair = (W == 0) ? 18 : 34;
    const int aoff = (W == 0) ? 16 : 0;

    float x[M];
#pragma unroll
    for (int i = 0; i < M; ++i) x[i] = xr[i] * s;
    if (W == 0) {
#pragma unroll
        for (int i = 0; i < M; ++i) {
            float d = x[i] - y;
            acc[i] = fmaf(d, d, acc[i]);
        }
    }
    int k = 0;
#pragma unroll
    for (int i = 0; i < M; ++i) {
#pragma unroll
        for (int j = i + 1; j < M; ++j) {
            if (k >= base && k < base + npair) {
                float d = x[i] - x[j];
                acc[aoff + k - base] = fmaf(d, d, acc[aoff + k - base]);
            }
            ++k;
        }
    }
}

// -------- per-wave main loop: reg-direct loads, 2-deep, spill-free ---------
// R4 PM: ty[16]+sw[16] pushed live state past 128 VGPR -> 34 MB scratch.
// v5: scale via uniform s_loads, target via 1-ahead rolling regs (W==0
// path only), loads in saddr form (uniform base + lane).  Live set ~95.
template<int W>
static __device__ __forceinline__ void k1_body(
    const float* __restrict__ preds,  // + base_u (scalar): b*256*L + l0
    const float* __restrict__ targ,   // + b*V*L + l0 (scalar; W==0 only)
    const float* __restrict__ scale,  // uniform -> SGPR
    size_t Ls, float wl, int lane, float* __restrict__ acc)
{
    float xa[M], xb[M];
    float ya = 0.0f, yb = 0.0f;
#pragma unroll
    for (int i = 0; i < M; ++i) xa[i] = (preds + (size_t)(i * 16) * Ls)[lane];
    if (W == 0) ya = targ[lane];      // raw target v=0

#pragma unroll
    for (int h = 0; h < 8; ++h) {
        const int v0 = 2 * h, v1 = 2 * h + 1;
#pragma unroll
        for (int i = 0; i < M; ++i)   // prefetch v1 over compute(v0)
            xb[i] = (preds + (size_t)(i * 16 + v1) * Ls)[lane];
        if (W == 0) yb = (targ + (size_t)v1 * Ls)[lane];
        {
            float s = scale[v0] * wl;
            pairs_one<W>(xa, s, (W == 0) ? ya * s : 0.0f, acc);
        }
        if (h < 7) {
#pragma unroll
            for (int i = 0; i < M; ++i)  // prefetch v0+2 over compute(v1)
                xa[i] = (preds + (size_t)(i * 16 + v0 + 2) * Ls)[lane];
            if (W == 0) ya = (targ + (size_t)(v0 + 2) * Ls)[lane];
        }
        {
            float s = scale[v1] * wl;
            pairs_one<W>(xb, s, (W == 0) ? yb * s : 0.0f, acc);
        }
    }
}

// -------- Fused kernel: pair-sums (reg-direct) + LDS transpose + MFMA ------
// Block (pb, b) owns one 64-l chunk.  Barrier-free main loop (R3 PM: all
// blocks resident => wall = per-block latency; barrier vmcnt(0) drains were
// the cost).  LDS = 18 KB sld only; target ~95-110 VGPR -> 16 waves/CU.
__global__ __launch_bounds__(256, 2)
void k1_fused(const float* __restrict__ preds, const float* __restrict__ target,
              const float* __restrict__ weights, const float* __restrict__ scale,
              const float* __restrict__ masks, float* __restrict__ partial,
              float* __restrict__ out, int L)
{
    __shared__ unsigned short sld[144 * 64];      // 18 KB bf16 S tile

    const int t = (int)threadIdx.x;
    const int lane = t & 63, wave = t >> 6;
    const int pb = (int)blockIdx.x;
    const int b  = (int)blockIdx.y;
    const int l0 = pb * 64;

    if (pb == 0 && b == 0 && t == 0) out[0] = 0.0f;   // k3b atomics ordered after

    // pad rows 136..143 = 0 (tile 8's upper half; ordered by the barrier below)
    ((unsigned int*)sld)[136 * 32 + t] = 0;

    const size_t Ls = (size_t)L;
    const float wl = weights[l0 + lane];

    const float* pB = preds + (size_t)b * 256 * Ls + l0;    // scalar base
    const float* tB = target + (size_t)b * V * Ls + l0;     // scalar base

    float acc[34];
#pragma unroll
    for (int r = 0; r < 34; ++r) acc[r] = 0.0f;

    switch (wave) {
        case 0: k1_body<0>(pB, tB, scale, Ls, wl, lane, acc); break;
        case 1: k1_body<1>(pB, tB, scale, Ls, wl, lane, acc); break;
        case 2: k1_body<2>(pB, tB, scale, Ls, wl, lane, acc); break;
        default: k1_body<3>(pB, tB, scale, Ls, wl, lane, acc); break;
    }

    // ---- acc -> S_lds, XOR-swizzled (row stride 128 B would be a 16-way
    // bank conflict on the b128 fragment reads; XOR of row&7 into bits[3:5]
    // of the short index spreads rows over 8 slots, residual 2-way = free)
#pragma unroll
    for (int r = 0; r < 34; ++r) {
        const int R = 34 * wave + r;
        sld[R * 64 + (lane ^ ((R & 7) << 3))] = f2bf(acc[r]);
    }
    __syncthreads();                              // cross-wave: tiles mix writers

    const int ntile = (wave == 3) ? 3 : 2;        // wave3 also owns tile 8
    f32x4 pacc[3][2];
#pragma unroll
    for (int ti = 0; ti < 3; ++ti)
#pragma unroll
        for (int pt = 0; pt < 2; ++pt)
            pacc[ti][pt] = (f32x4){0.f, 0.f, 0.f, 0.f};

    // ---- MFMA: pacc += S_tile x mask^T (layouts mirrored from verified k2)
#pragma unroll
    for (int ks = 0; ks < 2; ++ks) {
        bf16x8 bfr[2];
#pragma unroll
        for (int pt = 0; pt < 2; ++pt) {
            // B-frag: p = pt*16+(lane&15), 8 contig l; 0/1 -> bf16 = hi16
            const float* mp = masks + (size_t)(pt * 16 + (lane & 15)) * Ls
                            + l0 + ks * 32 + (lane >> 4) * 8;
            u32x4 m0 = *(const u32x4*)mp;
            u32x4 m1 = *(const u32x4*)(mp + 4);
            union { unsigned int u[4]; bf16x8 v; } bb;
            bb.u[0] = __builtin_amdgcn_perm(m0.y, m0.x, 0x07060302);
            bb.u[1] = __builtin_amdgcn_perm(m0.w, m0.z, 0x07060302);
            bb.u[2] = __builtin_amdgcn_perm(m1.y, m1.x, 0x07060302);
            bb.u[3] = __builtin_amdgcn_perm(m1.w, m1.z, 0x07060302);
            bfr[pt] = bb.v;
        }
#pragma unroll
        for (int ti = 0; ti < 3; ++ti) {
            if (ti >= ntile) continue;            // wave-uniform
            const int tile = (ti == 2) ? 8 : (wave + ti * 4);
            const bf16x8 a = *(const bf16x8*)&sld[
                (tile * 16 + (lane & 15)) * 64 +
                ((ks * 32 + (lane >> 4) * 8) ^ ((lane & 7) << 3))];
            pacc[ti][0] = __builtin_amdgcn_mfma_f32_16x16x32_bf16(
                a, bfr[0], pacc[ti][0], 0, 0, 0);
            pacc[ti][1] = __builtin_amdgcn_mfma_f32_16x16x32_bf16(
                a, bfr[1], pacc[ti][1], 0, 0, 0);
        }
    }

    // ---- store partial D2 for this (pb, b): [136][32] f32 -----------------
    float* P = partial + (size_t)(pb * 2 + b) * (NROWB * PMASK);
#pragma unroll
    for (int ti = 0; ti < 3; ++ti) {
        if (ti >= ntile) continue;
        const int tile = (ti == 2) ? 8 : (wave + ti * 4);
#pragma unroll
        for (int pt = 0; pt < 2; ++pt)
#pragma unroll
            for (int reg = 0; reg < 4; ++reg) {
                const int row = tile * 16 + (lane >> 4) * 4 + reg;
                if (row < NROWB)                  // drop pad rows 136..143
                    P[row * 32 + pt * 16 + (lane & 15)] = pacc[ti][pt][reg];
            }
    }
}

// -------- k3a: parallel pb-group sum: 34 x 30 blocks, 21 pb each -----------
__global__ __launch_bounds__(256, 2)
void k3a_reduce(const float* __restrict__ P, float* __restrict__ P2)
{
    const int t = (int)threadIdx.x;
    const int e = (int)blockIdx.x * 256 + t;      // 0..8703 = b*4352+row*32+p
    const int spl = (int)blockIdx.y;              // 0..29

    const float* p = P + (size_t)(spl * QPB) * PBSTRIDE + e;
    float a0 = 0.f, a1 = 0.f, a2 = 0.f;
#pragma unroll
    for (int q = 0; q < QPB; q += 3) {            // 21 = 7*3, all independent
        a0 += p[(size_t)(q    ) * PBSTRIDE];
        a1 += p[(size_t)(q + 1) * PBSTRIDE];
        a2 += p[(size_t)(q + 2) * PBSTRIDE];
    }
    P2[(size_t)spl * NE + e] = (a0 + a1) + a2;
}

// -------- k3b: final 30-sum (L2-resident), sqrt, weighted reduce, atomic ---
__global__ __launch_bounds__(256, 2)
void k3b_finalize(const float* __restrict__ P2, const int* __restrict__ beta_p,
                  float* __restrict__ out)
{
    const int t = (int)threadIdx.x;
    const int e = (int)blockIdx.x * 256 + t;      // 0..8703

    float a0 = 0.f, a1 = 0.f, a2 = 0.f;
#pragma unroll
    for (int q = 0; q < SPLIT; q += 3) {          // 30 independent loads
        a0 += P2[(size_t)(q    ) * NE + e];
        a1 += P2[(size_t)(q + 1) * NE + e];
        a2 += P2[(size_t)(q + 2) * NE + e];
    }
    float d2 = fmaxf((a0 + a1) + a2, 0.0f);
    float beta = (float)beta_p[0];
    float d = (beta == 1.0f) ? sqrtf(d2) : powf(d2, 0.5f * beta);

    const float wa = 1.0f / (float)(BS * M);
    const float wb = -1.0f / (float)(BS * M * (M - 1));
    const int row_g = e >> 5;                     // b*136 + row
    const int local = row_g % NROWB;
    float sum = ((local < M) ? wa : wb) * d;

    const int lane = t & 63, wv = t >> 6;
#pragma unroll
    for (int off = 32; off > 0; off >>= 1)
        sum += __shfl_down(sum, off, 64);
    __shared__ float red[4];
    if (lane == 0) red[wv] = sum;
    __syncthreads();
    if (t == 0)
        atomicAdd(out, red[0] + red[1] + red[2] + red[3]);
}

extern "C" void kernel_launch(void* const* d_in, const int* in_sizes, int n_in,
                              void* d_out, int out_size, void* d_ws, size_t ws_size,
                              hipStream_t stream)
{
    const float* preds   = (const float*)d_in[0];
    const float* target  = (const float*)d_in[1];
    const float* weights = (const float*)d_in[2];
    const float* scale   = (const float*)d_in[3];
    const float* masks   = (const float*)d_in[4];
    const int*   beta    = (const int*)d_in[5];
    float* out = (float*)d_out;

    int L = in_sizes[2];   // 40320 = NPB*64

    float* partial = (float*)d_ws;                // 630*2*136*32 f32 = 21.9 MB
    size_t p_bytes = (size_t)NPB * 2 * NROWB * PMASK * sizeof(float);
    float* partial2 = (float*)((char*)d_ws + ((p_bytes + 255) & ~(size_t)255));
                                                  // 30*8704 f32 = 1.04 MB

    dim3 g1(NPB, BS);                             // 630 x 2 = 1260 blocks
    k1_fused<<<g1, 256, 0, stream>>>(preds, target, weights, scale, masks,
                                     partial, out, L);

    dim3 g3a(NE / 256, SPLIT);                    // 34 x 30
    k3a_reduce<<<g3a, 256, 0, stream>>>(partial, partial2);

    k3b_finalize<<<NE / 256, 256, 0, stream>>>(partial2, beta, out);
}

// Round 6
// 200.309 us; speedup vs baseline: 1.0838x; 1.0838x over previous
//
#include <hip/hip_runtime.h>
#include <math.h>

// Shapes fixed by setup_inputs(): bs=2, m=16, v=16, L=40320, P=32, beta=1
#define BS 2
#define M 16
#define V 16
#define NROWB 136           // per-batch rows: 16 target + 120 i<j pairs
#define NROWS 272           // BS * NROWB
#define PMASK 32
#define NPB 630             // l-chunks = blocks per batch (L = NPB*64)
#define NE 8704             // NROWS*PMASK output elements
#define PBSTRIDE 8704       // floats per pb step in partial (2*136*32)
#define SPLIT 30            // k3a pb-groups
#define QPB 21              // pb per group (630 = 30*21)

typedef __attribute__((ext_vector_type(8))) short bf16x8;
typedef __attribute__((ext_vector_type(4))) float f32x4;
typedef __attribute__((ext_vector_type(4))) unsigned int u32x4;

static __device__ __forceinline__ unsigned short f2bf(float x) {
    unsigned int u = __float_as_uint(x);
    unsigned int r = (u + 0x7FFFu + ((u >> 16) & 1u)) >> 16;
    return (unsigned short)r;
}

// -------- per-wave main loop: minimum live state, TLP-hidden latency -------
// R4/R5 PM: xa/xb double-buffer + scaled-copy + fat addressing > 128 VGPR
// -> 40 MB scratch spill.  v6: ONE x[16] loaded fresh per v, scaled
// IN PLACE; one per-lane base pointer (transient addr temps, no persistent
// SGPR/VGPR address arrays).  Live ~= x16+acc34+addr ~= 80 VGPR ->
// ~6 waves/SIMD resident; 16 indep 256B loads/v-step, latency hidden by
// occupancy (6 waves x ~576 cyc FMA >> 900 cyc HBM).
template<int W>
static __device__ __forceinline__ void k1_body(
    const float* __restrict__ pB,     // preds + b*256*Ls + l0 + lane (per-lane)
    const float* __restrict__ tB,     // target + b*V*Ls + l0 + lane (per-lane)
    const float* __restrict__ scale,  // uniform -> s_loads
    size_t Ls, float wl, float* __restrict__ acc)
{
    const int base = (W == 0) ? 0 : 34 * W - 16;  // first pair idx
    const int npair = (W == 0) ? 18 : 34;
    const int aoff = (W == 0) ? 16 : 0;

#pragma unroll
    for (int v = 0; v < V; ++v) {
        float x[M];
#pragma unroll
        for (int i = 0; i < M; ++i)
            x[i] = pB[(size_t)(i * 16 + v) * Ls];
        const float s = scale[v] * wl;
#pragma unroll
        for (int i = 0; i < M; ++i) x[i] *= s;
        if (W == 0) {
            const float y = tB[(size_t)v * Ls] * s;
#pragma unroll
            for (int i = 0; i < M; ++i) {
                float d = x[i] - y;
                acc[i] = fmaf(d, d, acc[i]);
            }
        }
        int k = 0;
#pragma unroll
        for (int i = 0; i < M; ++i) {
#pragma unroll
            for (int j = i + 1; j < M; ++j) {
                if (k >= base && k < base + npair) {
                    float d = x[i] - x[j];
                    acc[aoff + k - base] = fmaf(d, d, acc[aoff + k - base]);
                }
                ++k;
            }
        }
    }
}

// -------- Fused kernel: pair-sums (reg-direct) + LDS transpose + MFMA ------
// Block (pb, b) owns one 64-l chunk.  Barrier-free main loop (R3 PM: all
// blocks resident => wall = per-block latency; barrier vmcnt(0) drains were
// the cost).  LDS = 18 KB sld only.  launch_bounds(256,2) caps at 256 VGPR
// (non-binding at the ~80 target).
__global__ __launch_bounds__(256, 2)
void k1_fused(const float* __restrict__ preds, const float* __restrict__ target,
              const float* __restrict__ weights, const float* __restrict__ scale,
              const float* __restrict__ masks, float* __restrict__ partial,
              float* __restrict__ out, int L)
{
    __shared__ unsigned short sld[144 * 64];      // 18 KB bf16 S tile

    const int t = (int)threadIdx.x;
    const int lane = t & 63, wave = t >> 6;
    const int pb = (int)blockIdx.x;
    const int b  = (int)blockIdx.y;
    const int l0 = pb * 64;

    if (pb == 0 && b == 0 && t == 0) out[0] = 0.0f;   // k3b atomics ordered after

    // pad rows 136..143 = 0 (tile 8's upper half; ordered by the barrier below)
    ((unsigned int*)sld)[136 * 32 + t] = 0;

    const size_t Ls = (size_t)L;
    const float wl = weights[l0 + lane];

    const float* pB = preds + (size_t)b * 256 * Ls + l0 + lane;   // per-lane
    const float* tB = target + (size_t)b * V * Ls + l0 + lane;    // per-lane

    float acc[34];
#pragma unroll
    for (int r = 0; r < 34; ++r) acc[r] = 0.0f;

    switch (wave) {
        case 0: k1_body<0>(pB, tB, scale, Ls, wl, acc); break;
        case 1: k1_body<1>(pB, tB, scale, Ls, wl, acc); break;
        case 2: k1_body<2>(pB, tB, scale, Ls, wl, acc); break;
        default: k1_body<3>(pB, tB, scale, Ls, wl, acc); break;
    }

    // ---- acc -> S_lds, XOR-swizzled (row stride 128 B would be a 16-way
    // bank conflict on the b128 fragment reads; XOR of row&7 into bits[3:5]
    // of the short index spreads rows over 8 slots, residual 2-way = free)
#pragma unroll
    for (int r = 0; r < 34; ++r) {
        const int R = 34 * wave + r;
        sld[R * 64 + (lane ^ ((R & 7) << 3))] = f2bf(acc[r]);
    }
    __syncthreads();                              // cross-wave: tiles mix writers

    const int ntile = (wave == 3) ? 3 : 2;        // wave3 also owns tile 8
    f32x4 pacc[3][2];
#pragma unroll
    for (int ti = 0; ti < 3; ++ti)
#pragma unroll
        for (int pt = 0; pt < 2; ++pt)
            pacc[ti][pt] = (f32x4){0.f, 0.f, 0.f, 0.f};

    // ---- MFMA: pacc += S_tile x mask^T (layouts mirrored from verified k2)
#pragma unroll
    for (int ks = 0; ks < 2; ++ks) {
        bf16x8 bfr[2];
#pragma unroll
        for (int pt = 0; pt < 2; ++pt) {
            // B-frag: p = pt*16+(lane&15), 8 contig l; 0/1 -> bf16 = hi16
            const float* mp = masks + (size_t)(pt * 16 + (lane & 15)) * Ls
                            + l0 + ks * 32 + (lane >> 4) * 8;
            u32x4 m0 = *(const u32x4*)mp;
            u32x4 m1 = *(const u32x4*)(mp + 4);
            union { unsigned int u[4]; bf16x8 v; } bb;
            bb.u[0] = __builtin_amdgcn_perm(m0.y, m0.x, 0x07060302);
            bb.u[1] = __builtin_amdgcn_perm(m0.w, m0.z, 0x07060302);
            bb.u[2] = __builtin_amdgcn_perm(m1.y, m1.x, 0x07060302);
            bb.u[3] = __builtin_amdgcn_perm(m1.w, m1.z, 0x07060302);
            bfr[pt] = bb.v;
        }
#pragma unroll
        for (int ti = 0; ti < 3; ++ti) {
            if (ti >= ntile) continue;            // wave-uniform
            const int tile = (ti == 2) ? 8 : (wave + ti * 4);
            const bf16x8 a = *(const bf16x8*)&sld[
                (tile * 16 + (lane & 15)) * 64 +
                ((ks * 32 + (lane >> 4) * 8) ^ ((lane & 7) << 3))];
            pacc[ti][0] = __builtin_amdgcn_mfma_f32_16x16x32_bf16(
                a, bfr[0], pacc[ti][0], 0, 0, 0);
            pacc[ti][1] = __builtin_amdgcn_mfma_f32_16x16x32_bf16(
                a, bfr[1], pacc[ti][1], 0, 0, 0);
        }
    }

    // ---- store partial D2 for this (pb, b): [136][32] f32 -----------------
    float* P = partial + (size_t)(pb * 2 + b) * (NROWB * PMASK);
#pragma unroll
    for (int ti = 0; ti < 3; ++ti) {
        if (ti >= ntile) continue;
        const int tile = (ti == 2) ? 8 : (wave + ti * 4);
#pragma unroll
        for (int pt = 0; pt < 2; ++pt)
#pragma unroll
            for (int reg = 0; reg < 4; ++reg) {
                const int row = tile * 16 + (lane >> 4) * 4 + reg;
                if (row < NROWB)                  // drop pad rows 136..143
                    P[row * 32 + pt * 16 + (lane & 15)] = pacc[ti][pt][reg];
            }
    }
}

// -------- k3a: parallel pb-group sum: 34 x 30 blocks, 21 pb each -----------
__global__ __launch_bounds__(256, 2)
void k3a_reduce(const float* __restrict__ P, float* __restrict__ P2)
{
    const int t = (int)threadIdx.x;
    const int e = (int)blockIdx.x * 256 + t;      // 0..8703 = b*4352+row*32+p
    const int spl = (int)blockIdx.y;              // 0..29

    const float* p = P + (size_t)(spl * QPB) * PBSTRIDE + e;
    float a0 = 0.f, a1 = 0.f, a2 = 0.f;
#pragma unroll
    for (int q = 0; q < QPB; q += 3) {            // 21 = 7*3, all independent
        a0 += p[(size_t)(q    ) * PBSTRIDE];
        a1 += p[(size_t)(q + 1) * PBSTRIDE];
        a2 += p[(size_t)(q + 2) * PBSTRIDE];
    }
    P2[(size_t)spl * NE + e] = (a0 + a1) + a2;
}

// -------- k3b: final 30-sum (L2-resident), sqrt, weighted reduce, atomic ---
__global__ __launch_bounds__(256, 2)
void k3b_finalize(const float* __restrict__ P2, const int* __restrict__ beta_p,
                  float* __restrict__ out)
{
    const int t = (int)threadIdx.x;
    const int e = (int)blockIdx.x * 256 + t;      // 0..8703

    float a0 = 0.f, a1 = 0.f, a2 = 0.f;
#pragma unroll
    for (int q = 0; q < SPLIT; q += 3) {          // 30 independent loads
        a0 += P2[(size_t)(q    ) * NE + e];
        a1 += P2[(size_t)(q + 1) * NE + e];
        a2 += P2[(size_t)(q + 2) * NE + e];
    }
    float d2 = fmaxf((a0 + a1) + a2, 0.0f);
    float beta = (float)beta_p[0];
    float d = (beta == 1.0f) ? sqrtf(d2) : powf(d2, 0.5f * beta);

    const float wa = 1.0f / (float)(BS * M);
    const float wb = -1.0f / (float)(BS * M * (M - 1));
    const int row_g = e >> 5;                     // b*136 + row
    const int local = row_g % NROWB;
    float sum = ((local < M) ? wa : wb) * d;

    const int lane = t & 63, wv = t >> 6;
#pragma unroll
    for (int off = 32; off > 0; off >>= 1)
        sum += __shfl_down(sum, off, 64);
    __shared__ float red[4];
    if (lane == 0) red[wv] = sum;
    __syncthreads();
    if (t == 0)
        atomicAdd(out, red[0] + red[1] + red[2] + red[3]);
}

extern "C" void kernel_launch(void* const* d_in, const int* in_sizes, int n_in,
                              void* d_out, int out_size, void* d_ws, size_t ws_size,
                              hipStream_t stream)
{
    const float* preds   = (const float*)d_in[0];
    const float* target  = (const float*)d_in[1];
    const float* weights = (const float*)d_in[2];
    const float* scale   = (const float*)d_in[3];
    const float* masks   = (const float*)d_in[4];
    const int*   beta    = (const int*)d_in[5];
    float* out = (float*)d_out;

    int L = in_sizes[2];   // 40320 = NPB*64

    float* partial = (float*)d_ws;                // 630*2*136*32 f32 = 21.9 MB
    size_t p_bytes = (size_t)NPB * 2 * NROWB * PMASK * sizeof(float);
    float* partial2 = (float*)((char*)d_ws + ((p_bytes + 255) & ~(size_t)255));
                                                  // 30*8704 f32 = 1.04 MB

    dim3 g1(NPB, BS);                             // 630 x 2 = 1260 blocks
    k1_fused<<<g1, 256, 0, stream>>>(preds, target, weights, scale, masks,
                                     partial, out, L);

    dim3 g3a(NE / 256, SPLIT);                    // 34 x 30
    k3a_reduce<<<g3a, 256, 0, stream>>>(partial, partial2);

    k3b_finalize<<<NE / 256, 256, 0, stream>>>(partial2, beta, out);
}

// Round 7
// 150.623 us; speedup vs baseline: 1.4413x; 1.3299x over previous
//
#include <hip/hip_runtime.h>
#include <math.h>

// Shapes fixed by setup_inputs(): bs=2, m=16, v=16, L=40320, P=32, beta=1
#define BS 2
#define M 16
#define V 16
#define NROWB 136           // per-batch rows: 16 target + 120 i<j pairs
#define NROWS 272           // BS * NROWB
#define PMASK 32
#define NPB 630             // l-chunks = blocks per batch (L = NPB*64)
#define NE 8704             // NROWS*PMASK output elements
#define PBSTRIDE 8704       // floats per pb step in partial (2*136*32)
#define SPLIT 30            // k3a pb-groups
#define QPB 21              // pb per group (630 = 30*21)

typedef __attribute__((ext_vector_type(8))) short bf16x8;
typedef __attribute__((ext_vector_type(4))) float f32x4;
typedef __attribute__((ext_vector_type(4))) unsigned int u32x4;

// counted vmem wait (T4): N = outstanding global_load_lds instrs to LEAVE
#define VMW(n) asm volatile("s_waitcnt vmcnt(" #n ")" ::: "memory")

static __device__ __forceinline__ unsigned short f2bf(float x) {
    unsigned int u = __float_as_uint(x);
    unsigned int r = (u + 0x7FFFu + ((u >> 16) & 1u)) >> 16;
    return (unsigned short)r;
}

// -------- global->LDS DMA stage: 32 rows (16 i x 2 v) x 64 l f32 = 8 KB ----
// Row r = i*2 + vc (vc = v-v0).  Per wave: 2 instrs x 4 rows.  LDS dest is
// wave-uniform base + lane*16 B (== row r0+(lane>>4), col (lane&15)*16B).
static __device__ __forceinline__ void k1_stage(
    const float* __restrict__ preds, float* __restrict__ dst,
    int b, int v0, int l0, int L, int lane, int wave)
{
#pragma unroll
    for (int n = 0; n < 2; ++n) {
        int r0 = wave * 8 + n * 4;                // wave-uniform LDS row group
        int r = r0 + (lane >> 4);                 // this lane's row
        int grow = b * 256 + (r >> 1) * 16 + v0 + (r & 1);
        const float* g = preds + (size_t)grow * L + l0 + (lane & 15) * 4;
        __builtin_amdgcn_global_load_lds(
            (const __attribute__((address_space(1))) unsigned int*)g,
            (__attribute__((address_space(3))) unsigned int*)(dst + r0 * 64),
            16, 0, 0);
    }
}

// -------- per-2v-stage pair/target accumulation (R3-verified math/order) ---
template<int W>
static __device__ __forceinline__ void k1_chunk(
    const float* __restrict__ xsb,                // 32 rows x 64 f32, r=i*2+vc
    const float* __restrict__ targ,               // 16 raw targets (W==0 only)
    const float* __restrict__ scl,                // scale[16]
    float wl,                                     // weights[l] for this lane
    int v0, int lane, float* __restrict__ acc)
{
    const int base = (W == 0) ? 0 : 34 * W - 16;  // first pair idx
    const int npair = (W == 0) ? 18 : 34;
    const int aoff = (W == 0) ? 16 : 0;

#pragma unroll
    for (int vc = 0; vc < 2; ++vc) {
        const int v = v0 + vc;                    // compile-time after unroll
        float s = scl[v] * wl;
        float x[M];
#pragma unroll
        for (int i = 0; i < M; ++i)
            x[i] = xsb[(i * 2 + vc) * 64 + lane] * s;
        if (W == 0) {
            float y = targ[v] * s;
#pragma unroll
            for (int i = 0; i < M; ++i) {
                float d = x[i] - y;
                acc[i] = fmaf(d, d, acc[i]);
            }
        }
        int k = 0;
#pragma unroll
        for (int i = 0; i < M; ++i) {
#pragma unroll
            for (int j = i + 1; j < M; ++j) {
                if (k >= base && k < base + npair) {
                    float d = x[i] - x[j];
                    acc[aoff + k - base] = fmaf(d, d, acc[aoff + k - base]);
                }
                ++k;
            }
        }
    }
}

// -------- Fused kernel: counted-vmcnt staged pair-sums + MFMA tail ---------
// R4-R6 PM: reg-direct spills at a hard 128-VGPR wall (3x identical
// signature).  R3's staged form fits (124, no spill) but exposed a full
// DMA round-trip per stage via __syncthreads' vmcnt(0) drain.  v7 = R3
// skeleton + T3/T4: 4 x 8 KB buffers, 3-deep prefetch, raw s_barrier with
// counted vmcnt(4) (tail 2/0) -- two stages always in flight, never
// drained mid-loop.  sched_barrier(0) after each barrier (rule #18).
// All non-DMA vmem loads fenced to completion BEFORE first DMA so vmcnt
// counts only DMAs.  sld ALIASES xs[0..2] (dead after stage-7 barrier):
// LDS = 32 KB -> 4 blocks/CU.
__global__ __launch_bounds__(256, 2)
void k1_fused(const float* __restrict__ preds, const float* __restrict__ target,
              const float* __restrict__ weights, const float* __restrict__ scale,
              const float* __restrict__ masks, float* __restrict__ partial,
              float* __restrict__ out, int L)
{
    __shared__ float xs[4][2048];                 // 4 x 8 KB DMA buffers
    unsigned short* sld = (unsigned short*)&xs[0][0];   // 18.4 KB alias (post-loop)

    const int t = (int)threadIdx.x;
    const int lane = t & 63, wave = t >> 6;
    const int pb = (int)blockIdx.x;
    const int b  = (int)blockIdx.y;
    const int l0 = pb * 64;

    if (pb == 0 && b == 0 && t == 0) out[0] = 0.0f;   // k3b atomics ordered after

    const size_t Ls = (size_t)L;

    // prologue: ALL per-lane vmem loads, then drain, so loop vmcnt = DMAs only
    const float wl = weights[l0 + lane];
    float scl[V];
#pragma unroll
    for (int v = 0; v < V; ++v) scl[v] = scale[v];
    float targ[V];
    if (wave == 0) {
#pragma unroll
        for (int v = 0; v < V; ++v)
            targ[v] = target[(size_t)(b * V + v) * Ls + l0 + lane];
    }
    VMW(0);                                       // scalar loads complete
    __builtin_amdgcn_sched_barrier(0);

    // 3-deep prefetch prologue: DMA(0..2) -> xs[0..2]
    k1_stage(preds, &xs[0][0], b, 0, l0, L, lane, wave);
    k1_stage(preds, &xs[1][0], b, 2, l0, L, lane, wave);
    k1_stage(preds, &xs[2][0], b, 4, l0, L, lane, wave);

    float acc[34];
#pragma unroll
    for (int r = 0; r < 34; ++r) acc[r] = 0.0f;

#pragma unroll
    for (int s = 0; s < 8; ++s) {
        // wait DMA(s) only; keep DMA(s+1),(s+2) in flight (2 instrs each)
        if (s < 6)      { VMW(4); }
        else if (s == 6){ VMW(2); }
        else            { VMW(0); }
        __builtin_amdgcn_s_barrier();             // all waves: DMA(s) landed,
                                                  // compute(s-1) done
        __builtin_amdgcn_sched_barrier(0);        // pin ds_reads/issues below
        if (s < 5)                                // DMA(s+3) -> buf[(s+3)&3]
            k1_stage(preds, &xs[(s + 3) & 3][0], b, (s + 3) * 2, l0, L, lane, wave);
        const float* xsb = &xs[s & 3][0];
        switch (wave) {
            case 0: k1_chunk<0>(xsb, targ, scl, wl, s * 2, lane, acc); break;
            case 1: k1_chunk<1>(xsb, targ, scl, wl, s * 2, lane, acc); break;
            case 2: k1_chunk<2>(xsb, targ, scl, wl, s * 2, lane, acc); break;
            default: k1_chunk<3>(xsb, targ, scl, wl, s * 2, lane, acc); break;
        }
    }
    // post stage-7 barrier, xs[0..2] are dead everywhere -> sld alias safe

    // pad rows 136..143 = 0 (tile 8's upper half)
    ((unsigned int*)sld)[136 * 32 + t] = 0;

    // ---- acc -> S_lds, XOR-swizzled (row stride 128 B would be a 16-way
    // bank conflict on the b128 fragment reads; XOR of row&7 into bits[3:5]
    // of the short index spreads rows over 8 slots, residual 2-way = free)
#pragma unroll
    for (int r = 0; r < 34; ++r) {
        const int R = 34 * wave + r;
        sld[R * 64 + (lane ^ ((R & 7) << 3))] = f2bf(acc[r]);
    }
    __syncthreads();                              // cross-wave: tiles mix writers

    const int ntile = (wave == 3) ? 3 : 2;        // wave3 also owns tile 8
    f32x4 pacc[3][2];
#pragma unroll
    for (int ti = 0; ti < 3; ++ti)
#pragma unroll
        for (int pt = 0; pt < 2; ++pt)
            pacc[ti][pt] = (f32x4){0.f, 0.f, 0.f, 0.f};

    // ---- MFMA: pacc += S_tile x mask^T (layouts mirrored from verified k2)
#pragma unroll
    for (int ks = 0; ks < 2; ++ks) {
        bf16x8 bfr[2];
#pragma unroll
        for (int pt = 0; pt < 2; ++pt) {
            // B-frag: p = pt*16+(lane&15), 8 contig l; 0/1 -> bf16 = hi16
            const float* mp = masks + (size_t)(pt * 16 + (lane & 15)) * Ls
                            + l0 + ks * 32 + (lane >> 4) * 8;
            u32x4 m0 = *(const u32x4*)mp;
            u32x4 m1 = *(const u32x4*)(mp + 4);
            union { unsigned int u[4]; bf16x8 v; } bb;
            bb.u[0] = __builtin_amdgcn_perm(m0.y, m0.x, 0x07060302);
            bb.u[1] = __builtin_amdgcn_perm(m0.w, m0.z, 0x07060302);
            bb.u[2] = __builtin_amdgcn_perm(m1.y, m1.x, 0x07060302);
            bb.u[3] = __builtin_amdgcn_perm(m1.w, m1.z, 0x07060302);
            bfr[pt] = bb.v;
        }
#pragma unroll
        for (int ti = 0; ti < 3; ++ti) {
            if (ti >= ntile) continue;            // wave-uniform
            const int tile = (ti == 2) ? 8 : (wave + ti * 4);
            const bf16x8 a = *(const bf16x8*)&sld[
                (tile * 16 + (lane & 15)) * 64 +
                ((ks * 32 + (lane >> 4) * 8) ^ ((lane & 7) << 3))];
            pacc[ti][0] = __builtin_amdgcn_mfma_f32_16x16x32_bf16(
                a, bfr[0], pacc[ti][0], 0, 0, 0);
            pacc[ti][1] = __builtin_amdgcn_mfma_f32_16x16x32_bf16(
                a, bfr[1], pacc[ti][1], 0, 0, 0);
        }
    }

    // ---- store partial D2 for this (pb, b): [136][32] f32 -----------------
    float* P = partial + (size_t)(pb * 2 + b) * (NROWB * PMASK);
#pragma unroll
    for (int ti = 0; ti < 3; ++ti) {
        if (ti >= ntile) continue;
        const int tile = (ti == 2) ? 8 : (wave + ti * 4);
#pragma unroll
        for (int pt = 0; pt < 2; ++pt)
#pragma unroll
            for (int reg = 0; reg < 4; ++reg) {
                const int row = tile * 16 + (lane >> 4) * 4 + reg;
                if (row < NROWB)                  // drop pad rows 136..143
                    P[row * 32 + pt * 16 + (lane & 15)] = pacc[ti][pt][reg];
            }
    }
}

// -------- k3a: parallel pb-group sum: 34 x 30 blocks, 21 pb each -----------
__global__ __launch_bounds__(256, 2)
void k3a_reduce(const float* __restrict__ P, float* __restrict__ P2)
{
    const int t = (int)threadIdx.x;
    const int e = (int)blockIdx.x * 256 + t;      // 0..8703 = b*4352+row*32+p
    const int spl = (int)blockIdx.y;              // 0..29

    const float* p = P + (size_t)(spl * QPB) * PBSTRIDE + e;
    float a0 = 0.f, a1 = 0.f, a2 = 0.f;
#pragma unroll
    for (int q = 0; q < QPB; q += 3) {            // 21 = 7*3, all independent
        a0 += p[(size_t)(q    ) * PBSTRIDE];
        a1 += p[(size_t)(q + 1) * PBSTRIDE];
        a2 += p[(size_t)(q + 2) * PBSTRIDE];
    }
    P2[(size_t)spl * NE + e] = (a0 + a1) + a2;
}

// -------- k3b: final 30-sum (L2-resident), sqrt, weighted reduce, atomic ---
__global__ __launch_bounds__(256, 2)
void k3b_finalize(const float* __restrict__ P2, const int* __restrict__ beta_p,
                  float* __restrict__ out)
{
    const int t = (int)threadIdx.x;
    const int e = (int)blockIdx.x * 256 + t;      // 0..8703

    float a0 = 0.f, a1 = 0.f, a2 = 0.f;
#pragma unroll
    for (int q = 0; q < SPLIT; q += 3) {          // 30 independent loads
        a0 += P2[(size_t)(q    ) * NE + e];
        a1 += P2[(size_t)(q + 1) * NE + e];
        a2 += P2[(size_t)(q + 2) * NE + e];
    }
    float d2 = fmaxf((a0 + a1) + a2, 0.0f);
    float beta = (float)beta_p[0];
    float d = (beta == 1.0f) ? sqrtf(d2) : powf(d2, 0.5f * beta);

    const float wa = 1.0f / (float)(BS * M);
    const float wb = -1.0f / (float)(BS * M * (M - 1));
    const int row_g = e >> 5;                     // b*136 + row
    const int local = row_g % NROWB;
    float sum = ((local < M) ? wa : wb) * d;

    const int lane = t & 63, wv = t >> 6;
#pragma unroll
    for (int off = 32; off > 0; off >>= 1)
        sum += __shfl_down(sum, off, 64);
    __shared__ float red[4];
    if (lane == 0) red[wv] = sum;
    __syncthreads();
    if (t == 0)
        atomicAdd(out, red[0] + red[1] + red[2] + red[3]);
}

extern "C" void kernel_launch(void* const* d_in, const int* in_sizes, int n_in,
                              void* d_out, int out_size, void* d_ws, size_t ws_size,
                              hipStream_t stream)
{
    const float* preds   = (const float*)d_in[0];
    const float* target  = (const float*)d_in[1];
    const float* weights = (const float*)d_in[2];
    const float* scale   = (const float*)d_in[3];
    const float* masks   = (const float*)d_in[4];
    const int*   beta    = (const int*)d_in[5];
    float* out = (float*)d_out;

    int L = in_sizes[2];   // 40320 = NPB*64

    float* partial = (float*)d_ws;                // 630*2*136*32 f32 = 21.9 MB
    size_t p_bytes = (size_t)NPB * 2 * NROWB * PMASK * sizeof(float);
    float* partial2 = (float*)((char*)d_ws + ((p_bytes + 255) & ~(size_t)255));
                                                  // 30*8704 f32 = 1.04 MB

    dim3 g1(NPB, BS);                             // 630 x 2 = 1260 blocks
    k1_fused<<<g1, 256, 0, stream>>>(preds, target, weights, scale, masks,
                                     partial, out, L);

    dim3 g3a(NE / 256, SPLIT);                    // 34 x 30
    k3a_reduce<<<g3a, 256, 0, stream>>>(partial, partial2);

    k3b_finalize<<<NE / 256, 256, 0, stream>>>(partial2, beta, out);
}